// Round 3
// baseline (1177.577 us; speedup 1.0000x reference)
//
#include <hip/hip_runtime.h>
#include <hip/hip_fp16.h>
#include <math.h>

// ---------------------------------------------------------------------------
// GCN 4-layer forward, round 3:
//  - packed edge records (src:16 | fp16 weight:16) -> half the scatter traffic
//  - XCD-sliced aggregation (64B feature slice per XCD -> L2-resident gathers)
//  - fused scan+rsqrt, fused wtrans, fused agg4+log_softmax
// ---------------------------------------------------------------------------

typedef __bf16 bf16x8v __attribute__((ext_vector_type(8)));
typedef float f32x4 __attribute__((ext_vector_type(4)));

__device__ __forceinline__ unsigned short f2bf(float f) {
    union { float f; unsigned u; } v; v.f = f;
    unsigned r = (v.u + 0x7FFFu + ((v.u >> 16) & 1u)) >> 16;
    return (unsigned short)r;
}
__device__ __forceinline__ float bflo(unsigned u) {
    union { unsigned u; float f; } v; v.u = u << 16; return v.f;
}
__device__ __forceinline__ float bfhi(unsigned u) {
    union { unsigned u; float f; } v; v.u = u & 0xFFFF0000u; return v.f;
}
__device__ __forceinline__ float unpackw(unsigned p) {
    return __half2float(__ushort_as_half((unsigned short)(p >> 16)));
}

// ------------------------- CSR build ---------------------------------------

__global__ __launch_bounds__(256) void count_kernel(const int* __restrict__ dst,
                                                    int* __restrict__ counts, int E) {
    int e = blockIdx.x * 256 + threadIdx.x;
    if (e < E) atomicAdd(&counts[dst[e]], 1);
}

// exclusive scan over counts -> offs[0..N], plus rsq = rsqrt(deg+1)
__global__ __launch_bounds__(1024) void scan_rsq_kernel(const int* __restrict__ counts,
                                                        int* __restrict__ offs,
                                                        float* __restrict__ rsq, int N) {
    __shared__ int sums[1024];
    int tid = threadIdx.x;
    int chunk = (N + 1023) / 1024;
    int start = tid * chunk;
    int end = start + chunk; if (end > N) end = N;
    int s = 0;
    for (int i = start; i < end; i++) {
        int c = counts[i];
        rsq[i] = rsqrtf((float)c + 1.0f);
        s += c;
    }
    sums[tid] = s;
    __syncthreads();
    for (int off = 1; off < 1024; off <<= 1) {
        int v = (tid >= off) ? sums[tid - off] : 0;
        __syncthreads();
        sums[tid] += v;
        __syncthreads();
    }
    int base = (tid == 0) ? 0 : sums[tid - 1];
    for (int i = start; i < end; i++) {
        offs[i] = base;
        base += counts[i];
    }
    if (tid == 1023) offs[N] = sums[1023];
}

// packed edge record: src index (16b, N<65536) | fp16 weight (16b)
__global__ __launch_bounds__(256) void scatter_kernel(const int* __restrict__ src,
                                                      const int* __restrict__ dst,
                                                      const int* __restrict__ offs,
                                                      int* __restrict__ cursor,
                                                      const float* __restrict__ rsq,
                                                      unsigned* __restrict__ epk, int E) {
    int e = blockIdx.x * 256 + threadIdx.x;
    if (e < E) {
        int d = dst[e];
        int s = src[e];
        int pos = offs[d] + atomicAdd(&cursor[d], 1);
        float w = rsq[s] * rsq[d];
        unsigned p = (unsigned)s |
                     ((unsigned)__half_as_ushort(__float2half_rn(w)) << 16);
        epk[pos] = p;
    }
}

// ------------------------- dtype conversions -------------------------------

__global__ __launch_bounds__(256) void cvt_f2bf_kernel(const float* __restrict__ in,
                                                       unsigned short* __restrict__ out,
                                                       int n4) {
    int i = blockIdx.x * 256 + threadIdx.x;
    if (i < n4) {
        float4 v = reinterpret_cast<const float4*>(in)[i];
        ushort4 o;
        o.x = f2bf(v.x); o.y = f2bf(v.y); o.z = f2bf(v.z); o.w = f2bf(v.w);
        reinterpret_cast<ushort4*>(out)[i] = o;
    }
}

// all four weight transposes (fp32 [K][Nc] -> bf16 [Nc][K]) in one kernel
__global__ __launch_bounds__(256) void wtrans_all_kernel(
        const float* __restrict__ W1, const float* __restrict__ W2,
        const float* __restrict__ W3, const float* __restrict__ W4,
        unsigned short* __restrict__ Wt1, unsigned short* __restrict__ Wt2,
        unsigned short* __restrict__ Wt3, unsigned short* __restrict__ Wt4) {
    int i = blockIdx.x * 256 + threadIdx.x;
    if (i < 32768) {                         // W1: 128x256
        int k = i >> 8, n = i & 255;
        Wt1[n * 128 + k] = f2bf(W1[i]);
    } else if (i < 98304) {                  // W2: 256x256
        int j = i - 32768; int k = j >> 8, n = j & 255;
        Wt2[n * 256 + k] = f2bf(W2[j]);
    } else if (i < 163840) {                 // W3: 256x256
        int j = i - 98304; int k = j >> 8, n = j & 255;
        Wt3[n * 256 + k] = f2bf(W3[j]);
    } else if (i < 174080) {                 // W4: 256x40
        int j = i - 163840; int k = j / 40, n = j - k * 40;
        Wt4[n * 256 + k] = f2bf(W4[j]);
    }
}

// ------------------------- XCD-sliced aggregation --------------------------
// out[n] = sum_e w_e * G[src_e] + (1/deg_n) * G[n]  (+bias) (+relu), bf16 io.
// Feature dim split into SLICES slices of 16 dwords (64B). slice = blockIdx %
// SLICES so (with round-robin block->XCD dispatch) each XCD touches only its
// 1/SLICES of the feature matrix -> L2-resident gathers.
// Wave layout: lane = eg*16 + f; eg in [0,4) processes every 4th edge; f is
// the dword within the slice. Shuffle-reduce over eg at the end.
template <int F, int SLICES, bool BIAS, bool RELU>
__global__ __launch_bounds__(256) void agg_slice_kernel(
        const unsigned* __restrict__ G,      // bf16 rows, F/2 dwords per row
        const int* __restrict__ offs,
        const unsigned* __restrict__ epk,
        const float* __restrict__ rsq,
        const float* __restrict__ bias,
        unsigned* __restrict__ out, int N) {
    constexpr int rowU = F / 2;
    int slice = blockIdx.x % SLICES;
    int group = blockIdx.x / SLICES;
    int node = group * 4 + (threadIdx.x >> 6);
    if (node >= N) return;
    int lane = threadIdx.x & 63;
    int f = lane & 15;
    int eg = lane >> 4;
    int col = slice * 16 + f;

    float ax = 0.f, ay = 0.f;
    if (eg == 0) {
        float sn = rsq[node];
        sn *= sn;
        unsigned g = G[(size_t)node * rowU + col];
        ax = sn * bflo(g); ay = sn * bfhi(g);
    }
    int e = offs[node] + eg;
    int e1 = offs[node + 1];
    for (; e + 4 < e1; e += 8) {
        unsigned p0 = epk[e], p1 = epk[e + 4];
        int s0 = p0 & 0xFFFFu, s1 = p1 & 0xFFFFu;
        float w0 = unpackw(p0), w1 = unpackw(p1);
        unsigned g0 = G[(size_t)s0 * rowU + col];
        unsigned g1 = G[(size_t)s1 * rowU + col];
        ax = fmaf(w0, bflo(g0), ax); ay = fmaf(w0, bfhi(g0), ay);
        ax = fmaf(w1, bflo(g1), ax); ay = fmaf(w1, bfhi(g1), ay);
    }
    if (e < e1) {
        unsigned p0 = epk[e];
        int s0 = p0 & 0xFFFFu;
        float w0 = unpackw(p0);
        unsigned g0 = G[(size_t)s0 * rowU + col];
        ax = fmaf(w0, bflo(g0), ax); ay = fmaf(w0, bfhi(g0), ay);
    }
    // reduce over eg (xor 16 then 32 preserves f)
    ax += __shfl_xor(ax, 16, 64); ay += __shfl_xor(ay, 16, 64);
    ax += __shfl_xor(ax, 32, 64); ay += __shfl_xor(ay, 32, 64);
    if (eg == 0) {
        if (BIAS) {
            float2 b = *reinterpret_cast<const float2*>(bias + 2 * col);
            ax += b.x; ay += b.y;
        }
        if (RELU) { ax = fmaxf(ax, 0.f); ay = fmaxf(ay, 0.f); }
        unsigned p = (unsigned)f2bf(ax) | ((unsigned)f2bf(ay) << 16);
        out[(size_t)node * rowU + col] = p;
    }
}

// ------------------------- agg (40 feats) + log_softmax --------------------
__global__ __launch_bounds__(256) void agg40_softmax_kernel(
        const unsigned* __restrict__ G,      // bf16 rows, 20 dwords per row
        const int* __restrict__ offs,
        const unsigned* __restrict__ epk,
        const float* __restrict__ rsq,
        const float* __restrict__ bias,
        float* __restrict__ out, int N) {
    int lane = threadIdx.x & 63;
    int node = blockIdx.x * 4 + (threadIdx.x >> 6);
    if (node >= N) return;
    bool act = lane < 20;
    float lo = 0.f, hi = 0.f;
    float sn = rsq[node];
    sn *= sn;
    if (act) {
        unsigned g = G[(size_t)node * 20 + lane];
        lo = sn * bflo(g); hi = sn * bfhi(g);
    }
    int e = offs[node], e1 = offs[node + 1];
    for (; e + 1 < e1; e += 2) {
        unsigned p0 = epk[e], p1 = epk[e + 1];
        if (act) {
            int s0 = p0 & 0xFFFFu, s1 = p1 & 0xFFFFu;
            float w0 = unpackw(p0), w1 = unpackw(p1);
            unsigned g0 = G[(size_t)s0 * 20 + lane];
            unsigned g1 = G[(size_t)s1 * 20 + lane];
            lo = fmaf(w0, bflo(g0), lo); hi = fmaf(w0, bfhi(g0), hi);
            lo = fmaf(w1, bflo(g1), lo); hi = fmaf(w1, bfhi(g1), hi);
        }
    }
    if (e < e1) {
        unsigned p0 = epk[e];
        if (act) {
            int s0 = p0 & 0xFFFFu;
            float w0 = unpackw(p0);
            unsigned g0 = G[(size_t)s0 * 20 + lane];
            lo = fmaf(w0, bflo(g0), lo); hi = fmaf(w0, bfhi(g0), hi);
        }
    }
    if (act) { lo += bias[2 * lane]; hi += bias[2 * lane + 1]; }
    float m = act ? fmaxf(lo, hi) : -INFINITY;
    #pragma unroll
    for (int o = 32; o >= 1; o >>= 1) m = fmaxf(m, __shfl_xor(m, o, 64));
    float s = act ? (expf(lo - m) + expf(hi - m)) : 0.f;
    #pragma unroll
    for (int o = 32; o >= 1; o >>= 1) s += __shfl_xor(s, o, 64);
    float ls = logf(s);
    if (act) {
        float2 o2;
        o2.x = lo - m - ls;
        o2.y = hi - m - ls;
        *reinterpret_cast<float2*>(out + (size_t)node * 40 + 2 * lane) = o2;
    }
}

// ------------------------- bf16 MFMA GEMM ----------------------------------
// C[M][Nc] = A[M][K] @ Bt[Nc][K]^T  (+bias) (+relu), fp32 accum, bf16 out.
template <bool BIAS, bool RELU>
__global__ __launch_bounds__(256) void gemm_bf16(
        const unsigned short* __restrict__ A,   // [M][K] bf16
        const unsigned short* __restrict__ Bt,  // [Nc][K] bf16
        const float* __restrict__ bias,
        unsigned short* __restrict__ Cout,
        int M, int K, int Nc) {
    __shared__ __align__(16) unsigned short As[128 * 72];
    __shared__ __align__(16) unsigned short Bs[128 * 72];
    int tid = threadIdx.x;
    int lane = tid & 63;
    int wid = tid >> 6;
    int rowBase = blockIdx.y * 128;
    int colBase = blockIdx.x * 128;
    int waveM = (wid & 1) * 64;
    int waveN = (wid >> 1) * 64;

    f32x4 acc[4][4] = {};
    int lrow = lane & 15;
    int kgrp = (lane >> 4) * 8;

    for (int k0 = 0; k0 < K; k0 += 64) {
        #pragma unroll
        for (int i = 0; i < 4; i++) {
            int c = tid + 256 * i;
            int row = c >> 3;
            int kp = (c & 7) * 8;
            int4 av = make_int4(0, 0, 0, 0);
            int gr = rowBase + row;
            if (gr < M)
                av = *reinterpret_cast<const int4*>(A + (size_t)gr * K + k0 + kp);
            *reinterpret_cast<int4*>(&As[row * 72 + kp]) = av;
            int4 bv = make_int4(0, 0, 0, 0);
            int gc = colBase + row;
            if (gc < Nc)
                bv = *reinterpret_cast<const int4*>(Bt + (size_t)gc * K + k0 + kp);
            *reinterpret_cast<int4*>(&Bs[row * 72 + kp]) = bv;
        }
        __syncthreads();
        #pragma unroll
        for (int kk = 0; kk < 64; kk += 32) {
            bf16x8v af[4], bfr[4];
            #pragma unroll
            for (int t = 0; t < 4; t++) {
                af[t] = *reinterpret_cast<const bf16x8v*>(
                    &As[(waveM + t * 16 + lrow) * 72 + kk + kgrp]);
                bfr[t] = *reinterpret_cast<const bf16x8v*>(
                    &Bs[(waveN + t * 16 + lrow) * 72 + kk + kgrp]);
            }
            #pragma unroll
            for (int mt = 0; mt < 4; mt++)
                #pragma unroll
                for (int nt = 0; nt < 4; nt++)
                    acc[mt][nt] = __builtin_amdgcn_mfma_f32_16x16x32_bf16(
                        af[mt], bfr[nt], acc[mt][nt], 0, 0, 0);
        }
        __syncthreads();
    }

    #pragma unroll
    for (int mt = 0; mt < 4; mt++) {
        #pragma unroll
        for (int r = 0; r < 4; r++) {
            int row = rowBase + waveM + mt * 16 + (lane >> 4) * 4 + r;
            if (row >= M) continue;
            #pragma unroll
            for (int nt = 0; nt < 4; nt++) {
                int col = colBase + waveN + nt * 16 + (lane & 15);
                if (col >= Nc) continue;
                float v = acc[mt][nt][r];
                if (BIAS) v += bias[col];
                if (RELU) v = fmaxf(v, 0.f);
                Cout[(size_t)row * Nc + col] = f2bf(v);
            }
        }
    }
}

// ---------------------------------------------------------------------------

extern "C" void kernel_launch(void* const* d_in, const int* in_sizes, int n_in,
                              void* d_out, int out_size, void* d_ws, size_t ws_size,
                              hipStream_t stream) {
    const float* x  = (const float*)d_in[0];
    const int*   ei = (const int*)d_in[1];
    const float* W1 = (const float*)d_in[2];
    const float* b1 = (const float*)d_in[3];
    const float* W2 = (const float*)d_in[4];
    const float* b2 = (const float*)d_in[5];
    const float* W3 = (const float*)d_in[6];
    const float* b3 = (const float*)d_in[7];
    const float* W4 = (const float*)d_in[8];
    const float* b4 = (const float*)d_in[9];

    const int FIN = 128, HID = 256, C = 40;
    const int N = in_sizes[0] / FIN;   // 50000 (< 65536, required by edge pack)
    const int E = in_sizes[1] / 2;
    const int* src = ei;
    const int* dst = ei + E;

    char* w = (char*)d_ws;
    auto alloc = [&](size_t bytes) {
        char* p = w;
        w += (bytes + 255) & ~(size_t)255;
        return p;
    };
    int*   cc     = (int*)alloc((size_t)2 * N * 4);   // counts | cursor
    int*   counts = cc;
    int*   cursor = cc + N;
    int*   offs   = (int*)alloc((size_t)(N + 1) * 4);
    float* rsq    = (float*)alloc((size_t)N * 4);
    unsigned* epk = (unsigned*)alloc((size_t)E * 4);
    unsigned short* xb   = (unsigned short*)alloc((size_t)N * FIN * 2);
    unsigned short* aggx = (unsigned short*)alloc((size_t)N * FIN * 2);
    unsigned short* bufA = (unsigned short*)alloc((size_t)N * HID * 2);
    unsigned short* bufB = (unsigned short*)alloc((size_t)N * HID * 2);
    unsigned short* Wt1 = (unsigned short*)alloc((size_t)FIN * HID * 2);
    unsigned short* Wt2 = (unsigned short*)alloc((size_t)HID * HID * 2);
    unsigned short* Wt3 = (unsigned short*)alloc((size_t)HID * HID * 2);
    unsigned short* Wt4 = (unsigned short*)alloc((size_t)HID * C * 2);

    hipMemsetAsync(cc, 0, (size_t)2 * N * 4, stream);

    cvt_f2bf_kernel<<<(N * FIN / 4 + 255) / 256, 256, 0, stream>>>(x, xb, N * FIN / 4);
    wtrans_all_kernel<<<680, 256, 0, stream>>>(W1, W2, W3, W4, Wt1, Wt2, Wt3, Wt4);

    count_kernel<<<(E + 255) / 256, 256, 0, stream>>>(dst, counts, E);
    scan_rsq_kernel<<<1, 1024, 0, stream>>>(counts, offs, rsq, N);
    scatter_kernel<<<(E + 255) / 256, 256, 0, stream>>>(src, dst, offs, cursor, rsq,
                                                        epk, E);

    int grp = (N + 3) / 4;
    dim3 gHID((HID + 127) / 128, (N + 127) / 128);
    dim3 gC((C + 127) / 128, (N + 127) / 128);

    // Layer 1: aggregate x (128 feats, 4 slices) then GEMM(+b1, relu)
    agg_slice_kernel<128, 4, false, false>
        <<<4 * grp, 256, 0, stream>>>((const unsigned*)xb, offs, epk, rsq, nullptr,
                                      (unsigned*)aggx, N);
    gemm_bf16<true, true><<<gHID, 256, 0, stream>>>(aggx, Wt1, b1, bufA, N, FIN, HID);
    // Layer 2: GEMM -> agg(+b2, relu)
    gemm_bf16<false, false><<<gHID, 256, 0, stream>>>(bufA, Wt2, nullptr, bufB,
                                                      N, HID, HID);
    agg_slice_kernel<256, 8, true, true>
        <<<8 * grp, 256, 0, stream>>>((const unsigned*)bufB, offs, epk, rsq, b2,
                                      (unsigned*)bufA, N);
    // Layer 3: GEMM -> agg(+b3, relu)
    gemm_bf16<false, false><<<gHID, 256, 0, stream>>>(bufA, Wt3, nullptr, bufB,
                                                      N, HID, HID);
    agg_slice_kernel<256, 8, true, true>
        <<<8 * grp, 256, 0, stream>>>((const unsigned*)bufB, offs, epk, rsq, b3,
                                      (unsigned*)bufA, N);
    // Layer 4: GEMM (Nc=40) -> agg(+b4) + log_softmax fused
    gemm_bf16<false, false><<<gC, 256, 0, stream>>>(bufA, Wt4, nullptr, bufB,
                                                    N, HID, C);
    agg40_softmax_kernel<<<grp, 256, 0, stream>>>((const unsigned*)bufB, offs, epk,
                                                  rsq, b4, (float*)d_out, N);
}

// Round 4
// 786.906 us; speedup vs baseline: 1.4965x; 1.4965x over previous
//
#include <hip/hip_runtime.h>
#include <hip/hip_fp16.h>
#include <math.h>

// ---------------------------------------------------------------------------
// GCN 4-layer forward, round 4:
//  - features in fp16 everywhere; agg uses packed v_pk_fma_f16 (no unpack)
//  - row-per-wave coalesced gather, 4-edge unroll with hoisted loads
//  - scatter with precomputed ranks (no atomics in scatter)
//  - f16 MFMA GEMMs (same rate as bf16), fp32 accum everywhere that matters
// ---------------------------------------------------------------------------

typedef _Float16 f16x8 __attribute__((ext_vector_type(8)));
typedef float f32x4 __attribute__((ext_vector_type(4)));

__device__ __forceinline__ __half2 u2h2(unsigned u) {
    union { unsigned u; __half2 h; } v; v.u = u; return v.h;
}
__device__ __forceinline__ unsigned h22u(__half2 h) {
    union { unsigned u; __half2 h; } v; v.h = h; return v.u;
}
__device__ __forceinline__ float hlo(unsigned u) {
    return __half2float(__ushort_as_half((unsigned short)(u & 0xFFFFu)));
}
__device__ __forceinline__ float hhi(unsigned u) {
    return __half2float(__ushort_as_half((unsigned short)(u >> 16)));
}

// ------------------------- CSR build ---------------------------------------

// counts degree AND records each edge's rank within its destination bucket
__global__ __launch_bounds__(256) void count_kernel(const int* __restrict__ dst,
                                                    int* __restrict__ counts,
                                                    int* __restrict__ rank, int E) {
    int e = blockIdx.x * 256 + threadIdx.x;
    if (e < E) rank[e] = atomicAdd(&counts[dst[e]], 1);
}

// exclusive scan over counts -> offs[0..N], plus rsq = rsqrt(deg+1)
__global__ __launch_bounds__(1024) void scan_rsq_kernel(const int* __restrict__ counts,
                                                        int* __restrict__ offs,
                                                        float* __restrict__ rsq, int N) {
    __shared__ int sums[1024];
    int tid = threadIdx.x;
    int chunk = (N + 1023) / 1024;
    int start = tid * chunk;
    int end = start + chunk; if (end > N) end = N;
    int s = 0;
    for (int i = start; i < end; i++) {
        int c = counts[i];
        rsq[i] = rsqrtf((float)c + 1.0f);
        s += c;
    }
    sums[tid] = s;
    __syncthreads();
    for (int off = 1; off < 1024; off <<= 1) {
        int v = (tid >= off) ? sums[tid - off] : 0;
        __syncthreads();
        sums[tid] += v;
        __syncthreads();
    }
    int base = (tid == 0) ? 0 : sums[tid - 1];
    for (int i = start; i < end; i++) {
        offs[i] = base;
        base += counts[i];
    }
    if (tid == 1023) offs[N] = sums[1023];
}

// packed edge record: src index (16b, N<65536) | fp16 weight (16b). No atomics.
__global__ __launch_bounds__(256) void scatter_kernel(const int* __restrict__ src,
                                                      const int* __restrict__ dst,
                                                      const int* __restrict__ rank,
                                                      const int* __restrict__ offs,
                                                      const float* __restrict__ rsq,
                                                      unsigned* __restrict__ epk, int E) {
    int e = blockIdx.x * 256 + threadIdx.x;
    if (e < E) {
        int d = dst[e];
        int s = src[e];
        int pos = offs[d] + rank[e];
        float w = rsq[s] * rsq[d];
        epk[pos] = (unsigned)s |
                   ((unsigned)__half_as_ushort(__float2half_rn(w)) << 16);
    }
}

// ------------------------- dtype conversions -------------------------------

__global__ __launch_bounds__(256) void cvt_f2h_kernel(const float* __restrict__ in,
                                                      unsigned short* __restrict__ out,
                                                      int n4) {
    int i = blockIdx.x * 256 + threadIdx.x;
    if (i < n4) {
        float4 v = reinterpret_cast<const float4*>(in)[i];
        ushort4 o;
        o.x = __half_as_ushort(__float2half_rn(v.x));
        o.y = __half_as_ushort(__float2half_rn(v.y));
        o.z = __half_as_ushort(__float2half_rn(v.z));
        o.w = __half_as_ushort(__float2half_rn(v.w));
        reinterpret_cast<ushort4*>(out)[i] = o;
    }
}

// all four weight transposes (fp32 [K][Nc] -> fp16 [Nc][K]) in one kernel
__global__ __launch_bounds__(256) void wtrans_all_kernel(
        const float* __restrict__ W1, const float* __restrict__ W2,
        const float* __restrict__ W3, const float* __restrict__ W4,
        unsigned short* __restrict__ Wt1, unsigned short* __restrict__ Wt2,
        unsigned short* __restrict__ Wt3, unsigned short* __restrict__ Wt4) {
    int i = blockIdx.x * 256 + threadIdx.x;
    if (i < 32768) {                         // W1: 128x256
        int k = i >> 8, n = i & 255;
        Wt1[n * 128 + k] = __half_as_ushort(__float2half_rn(W1[i]));
    } else if (i < 98304) {                  // W2: 256x256
        int j = i - 32768; int k = j >> 8, n = j & 255;
        Wt2[n * 256 + k] = __half_as_ushort(__float2half_rn(W2[j]));
    } else if (i < 163840) {                 // W3: 256x256
        int j = i - 98304; int k = j >> 8, n = j & 255;
        Wt3[n * 256 + k] = __half_as_ushort(__float2half_rn(W3[j]));
    } else if (i < 174080) {                 // W4: 256x40
        int j = i - 163840; int k = j / 40, n = j - k * 40;
        Wt4[n * 256 + k] = __half_as_ushort(__float2half_rn(W4[j]));
    }
}

// ------------------------- fp16 row-per-wave aggregation -------------------
// out[n] = sum_e w_e * G[src_e] + (1/deg_n) * G[n]  (+bias) (+relu)
// One wave per node. H2 = half2 elements per lane (1 -> F=128, 2 -> F=256).
// Whole row read coalesced per edge; packed fp16 FMA accumulation; edges
// unrolled by 4 with all gathers hoisted for memory-level parallelism.
template <int H2, bool BIAS, bool RELU>
__global__ __launch_bounds__(256) void agg_f16_kernel(
        const unsigned* __restrict__ G,      // fp16 rows, 64*H2 dwords per row
        const int* __restrict__ offs,
        const unsigned* __restrict__ epk,
        const float* __restrict__ rsq,
        const float* __restrict__ bias,
        unsigned* __restrict__ out, int N) {
    constexpr int ROWU = 64 * H2;
    int lane = threadIdx.x & 63;
    int node = blockIdx.x * 4 + (threadIdx.x >> 6);
    if (node >= N) return;
    const unsigned* base = G + lane * H2;

    __half2 acc[H2];
    #pragma unroll
    for (int i = 0; i < H2; i++) acc[i] = u2h2(0u);

    int e = offs[node], e1 = offs[node + 1];
    for (; e + 3 < e1; e += 4) {
        unsigned p[4];
        int s[4];
        #pragma unroll
        for (int j = 0; j < 4; j++) { p[j] = epk[e + j]; s[j] = p[j] & 0xFFFFu; }
        unsigned g[4][H2];
        #pragma unroll
        for (int j = 0; j < 4; j++)
            #pragma unroll
            for (int i = 0; i < H2; i++)
                g[j][i] = base[(size_t)s[j] * ROWU + i];
        #pragma unroll
        for (int j = 0; j < 4; j++) {
            __half2 w2 = __half2half2(__ushort_as_half((unsigned short)(p[j] >> 16)));
            #pragma unroll
            for (int i = 0; i < H2; i++)
                acc[i] = __hfma2(w2, u2h2(g[j][i]), acc[i]);
        }
    }
    for (; e < e1; e++) {
        unsigned p0 = epk[e];
        int s0 = p0 & 0xFFFFu;
        __half2 w2 = __half2half2(__ushort_as_half((unsigned short)(p0 >> 16)));
        #pragma unroll
        for (int i = 0; i < H2; i++)
            acc[i] = __hfma2(w2, u2h2(base[(size_t)s0 * ROWU + i]), acc[i]);
    }

    float sn = rsq[node];
    sn *= sn;
    #pragma unroll
    for (int i = 0; i < H2; i++) {
        unsigned sv = base[(size_t)node * ROWU + i];
        float2 f = __half22float2(acc[i]);
        f.x = fmaf(sn, hlo(sv), f.x);
        f.y = fmaf(sn, hhi(sv), f.y);
        if (BIAS) {
            float2 b = reinterpret_cast<const float2*>(bias)[lane * H2 + i];
            f.x += b.x; f.y += b.y;
        }
        if (RELU) { f.x = fmaxf(f.x, 0.f); f.y = fmaxf(f.y, 0.f); }
        out[(size_t)node * ROWU + lane * H2 + i] = h22u(__floats2half2_rn(f.x, f.y));
    }
}

// ------------------------- agg (40 feats) + log_softmax --------------------
__global__ __launch_bounds__(256) void agg40_softmax_kernel(
        const unsigned* __restrict__ G,      // fp16 rows, 20 dwords per row
        const int* __restrict__ offs,
        const unsigned* __restrict__ epk,
        const float* __restrict__ rsq,
        const float* __restrict__ bias,
        float* __restrict__ out, int N) {
    int lane = threadIdx.x & 63;
    int node = blockIdx.x * 4 + (threadIdx.x >> 6);
    if (node >= N) return;
    bool act = lane < 20;
    __half2 acch = u2h2(0u);
    int e = offs[node], e1 = offs[node + 1];
    for (; e + 1 < e1; e += 2) {
        unsigned p0 = epk[e], p1 = epk[e + 1];
        if (act) {
            int s0 = p0 & 0xFFFFu, s1 = p1 & 0xFFFFu;
            __half2 w0 = __half2half2(__ushort_as_half((unsigned short)(p0 >> 16)));
            __half2 w1 = __half2half2(__ushort_as_half((unsigned short)(p1 >> 16)));
            unsigned g0 = G[(size_t)s0 * 20 + lane];
            unsigned g1 = G[(size_t)s1 * 20 + lane];
            acch = __hfma2(w0, u2h2(g0), acch);
            acch = __hfma2(w1, u2h2(g1), acch);
        }
    }
    if (e < e1 && act) {
        unsigned p0 = epk[e];
        int s0 = p0 & 0xFFFFu;
        __half2 w0 = __half2half2(__ushort_as_half((unsigned short)(p0 >> 16)));
        acch = __hfma2(w0, u2h2(G[(size_t)s0 * 20 + lane]), acch);
    }
    float lo = 0.f, hi = 0.f;
    if (act) {
        float sn = rsq[node];
        sn *= sn;
        unsigned sv = G[(size_t)node * 20 + lane];
        float2 f = __half22float2(acch);
        lo = fmaf(sn, hlo(sv), f.x) + bias[2 * lane];
        hi = fmaf(sn, hhi(sv), f.y) + bias[2 * lane + 1];
    }
    float m = act ? fmaxf(lo, hi) : -INFINITY;
    #pragma unroll
    for (int o = 32; o >= 1; o >>= 1) m = fmaxf(m, __shfl_xor(m, o, 64));
    float s = act ? (expf(lo - m) + expf(hi - m)) : 0.f;
    #pragma unroll
    for (int o = 32; o >= 1; o >>= 1) s += __shfl_xor(s, o, 64);
    float ls = logf(s);
    if (act) {
        float2 o2;
        o2.x = lo - m - ls;
        o2.y = hi - m - ls;
        *reinterpret_cast<float2*>(out + (size_t)node * 40 + 2 * lane) = o2;
    }
}

// ------------------------- f16 MFMA GEMM -----------------------------------
// C[M][Nc] = A[M][K] @ Bt[Nc][K]^T  (+bias) (+relu), fp32 accum, fp16 out.
template <bool BIAS, bool RELU>
__global__ __launch_bounds__(256) void gemm_f16(
        const unsigned short* __restrict__ A,   // [M][K] fp16
        const unsigned short* __restrict__ Bt,  // [Nc][K] fp16
        const float* __restrict__ bias,
        unsigned short* __restrict__ Cout,
        int M, int K, int Nc) {
    __shared__ __align__(16) unsigned short As[128 * 72];
    __shared__ __align__(16) unsigned short Bs[128 * 72];
    int tid = threadIdx.x;
    int lane = tid & 63;
    int wid = tid >> 6;
    int rowBase = blockIdx.y * 128;
    int colBase = blockIdx.x * 128;
    int waveM = (wid & 1) * 64;
    int waveN = (wid >> 1) * 64;

    f32x4 acc[4][4] = {};
    int lrow = lane & 15;
    int kgrp = (lane >> 4) * 8;

    for (int k0 = 0; k0 < K; k0 += 64) {
        #pragma unroll
        for (int i = 0; i < 4; i++) {
            int c = tid + 256 * i;
            int row = c >> 3;
            int kp = (c & 7) * 8;
            int4 av = make_int4(0, 0, 0, 0);
            int gr = rowBase + row;
            if (gr < M)
                av = *reinterpret_cast<const int4*>(A + (size_t)gr * K + k0 + kp);
            *reinterpret_cast<int4*>(&As[row * 72 + kp]) = av;
            int4 bv = make_int4(0, 0, 0, 0);
            int gc = colBase + row;
            if (gc < Nc)
                bv = *reinterpret_cast<const int4*>(Bt + (size_t)gc * K + k0 + kp);
            *reinterpret_cast<int4*>(&Bs[row * 72 + kp]) = bv;
        }
        __syncthreads();
        #pragma unroll
        for (int kk = 0; kk < 64; kk += 32) {
            f16x8 af[4], bfr[4];
            #pragma unroll
            for (int t = 0; t < 4; t++) {
                af[t] = *reinterpret_cast<const f16x8*>(
                    &As[(waveM + t * 16 + lrow) * 72 + kk + kgrp]);
                bfr[t] = *reinterpret_cast<const f16x8*>(
                    &Bs[(waveN + t * 16 + lrow) * 72 + kk + kgrp]);
            }
            #pragma unroll
            for (int mt = 0; mt < 4; mt++)
                #pragma unroll
                for (int nt = 0; nt < 4; nt++)
                    acc[mt][nt] = __builtin_amdgcn_mfma_f32_16x16x32_f16(
                        af[mt], bfr[nt], acc[mt][nt], 0, 0, 0);
        }
        __syncthreads();
    }

    #pragma unroll
    for (int mt = 0; mt < 4; mt++) {
        #pragma unroll
        for (int r = 0; r < 4; r++) {
            int row = rowBase + waveM + mt * 16 + (lane >> 4) * 4 + r;
            if (row >= M) continue;
            #pragma unroll
            for (int nt = 0; nt < 4; nt++) {
                int col = colBase + waveN + nt * 16 + (lane & 15);
                if (col >= Nc) continue;
                float v = acc[mt][nt][r];
                if (BIAS) v += bias[col];
                if (RELU) v = fmaxf(v, 0.f);
                Cout[(size_t)row * Nc + col] = __half_as_ushort(__float2half_rn(v));
            }
        }
    }
}

// ---------------------------------------------------------------------------

extern "C" void kernel_launch(void* const* d_in, const int* in_sizes, int n_in,
                              void* d_out, int out_size, void* d_ws, size_t ws_size,
                              hipStream_t stream) {
    const float* x  = (const float*)d_in[0];
    const int*   ei = (const int*)d_in[1];
    const float* W1 = (const float*)d_in[2];
    const float* b1 = (const float*)d_in[3];
    const float* W2 = (const float*)d_in[4];
    const float* b2 = (const float*)d_in[5];
    const float* W3 = (const float*)d_in[6];
    const float* b3 = (const float*)d_in[7];
    const float* W4 = (const float*)d_in[8];
    const float* b4 = (const float*)d_in[9];

    const int FIN = 128, HID = 256, C = 40;
    const int N = in_sizes[0] / FIN;   // 50000 (< 65536, required by edge pack)
    const int E = in_sizes[1] / 2;
    const int* src = ei;
    const int* dst = ei + E;

    char* w = (char*)d_ws;
    auto alloc = [&](size_t bytes) {
        char* p = w;
        w += (bytes + 255) & ~(size_t)255;
        return p;
    };
    int*   counts = (int*)alloc((size_t)N * 4);
    int*   offs   = (int*)alloc((size_t)(N + 1) * 4);
    float* rsq    = (float*)alloc((size_t)N * 4);
    int*   rank   = (int*)alloc((size_t)E * 4);
    unsigned* epk = (unsigned*)alloc((size_t)E * 4);
    unsigned short* xb   = (unsigned short*)alloc((size_t)N * FIN * 2);
    unsigned short* aggx = (unsigned short*)alloc((size_t)N * FIN * 2);
    unsigned short* bufA = (unsigned short*)alloc((size_t)N * HID * 2);
    unsigned short* bufB = (unsigned short*)alloc((size_t)N * HID * 2);
    unsigned short* Wt1 = (unsigned short*)alloc((size_t)FIN * HID * 2);
    unsigned short* Wt2 = (unsigned short*)alloc((size_t)HID * HID * 2);
    unsigned short* Wt3 = (unsigned short*)alloc((size_t)HID * HID * 2);
    unsigned short* Wt4 = (unsigned short*)alloc((size_t)HID * C * 2);

    hipMemsetAsync(counts, 0, (size_t)N * 4, stream);

    cvt_f2h_kernel<<<(N * FIN / 4 + 255) / 256, 256, 0, stream>>>(x, xb, N * FIN / 4);
    wtrans_all_kernel<<<680, 256, 0, stream>>>(W1, W2, W3, W4, Wt1, Wt2, Wt3, Wt4);

    count_kernel<<<(E + 255) / 256, 256, 0, stream>>>(dst, counts, rank, E);
    scan_rsq_kernel<<<1, 1024, 0, stream>>>(counts, offs, rsq, N);
    scatter_kernel<<<(E + 255) / 256, 256, 0, stream>>>(src, dst, rank, offs, rsq,
                                                        epk, E);

    int grp = (N + 3) / 4;
    dim3 gHID((HID + 127) / 128, (N + 127) / 128);
    dim3 gC((C + 127) / 128, (N + 127) / 128);

    // Layer 1: aggregate x (128 feats) then GEMM(+b1, relu)
    agg_f16_kernel<1, false, false>
        <<<grp, 256, 0, stream>>>((const unsigned*)xb, offs, epk, rsq, nullptr,
                                  (unsigned*)aggx, N);
    gemm_f16<true, true><<<gHID, 256, 0, stream>>>(aggx, Wt1, b1, bufA, N, FIN, HID);
    // Layer 2: GEMM -> agg(+b2, relu)
    gemm_f16<false, false><<<gHID, 256, 0, stream>>>(bufA, Wt2, nullptr, bufB,
                                                     N, HID, HID);
    agg_f16_kernel<2, true, true>
        <<<grp, 256, 0, stream>>>((const unsigned*)bufB, offs, epk, rsq, b2,
                                  (unsigned*)bufA, N);
    // Layer 3: GEMM -> agg(+b3, relu)
    gemm_f16<false, false><<<gHID, 256, 0, stream>>>(bufA, Wt3, nullptr, bufB,
                                                     N, HID, HID);
    agg_f16_kernel<2, true, true>
        <<<grp, 256, 0, stream>>>((const unsigned*)bufB, offs, epk, rsq, b3,
                                  (unsigned*)bufA, N);
    // Layer 4: GEMM (Nc=40) -> agg(+b4) + log_softmax fused
    gemm_f16<false, false><<<gC, 256, 0, stream>>>(bufA, Wt4, nullptr, bufB,
                                                   N, HID, C);
    agg40_softmax_kernel<<<grp, 256, 0, stream>>>((const unsigned*)bufB, offs, epk,
                                                  rsq, b4, (float*)d_out, N);
}

// Round 5
// 665.677 us; speedup vs baseline: 1.7690x; 1.1821x over previous
//
#include <hip/hip_runtime.h>
#include <hip/hip_fp16.h>
#include <math.h>

// ---------------------------------------------------------------------------
// GCN 4-layer forward, round 5:
//  - round-4 structure (fp16 agg + f16 MFMA GEMMs + rank-based scatter)
//  - single-block scan replaced by 3-phase multi-block scan (was 132 us at
//    0.17% occupancy; now ~10 us total)
// ---------------------------------------------------------------------------

typedef _Float16 f16x8 __attribute__((ext_vector_type(8)));
typedef float f32x4 __attribute__((ext_vector_type(4)));

__device__ __forceinline__ __half2 u2h2(unsigned u) {
    union { unsigned u; __half2 h; } v; v.u = u; return v.h;
}
__device__ __forceinline__ unsigned h22u(__half2 h) {
    union { unsigned u; __half2 h; } v; v.h = h; return v.u;
}
__device__ __forceinline__ float hlo(unsigned u) {
    return __half2float(__ushort_as_half((unsigned short)(u & 0xFFFFu)));
}
__device__ __forceinline__ float hhi(unsigned u) {
    return __half2float(__ushort_as_half((unsigned short)(u >> 16)));
}

// ------------------------- CSR build ---------------------------------------

// counts degree AND records each edge's rank within its destination bucket
__global__ __launch_bounds__(256) void count_kernel(const int* __restrict__ dst,
                                                    int* __restrict__ counts,
                                                    int* __restrict__ rank, int E) {
    int e = blockIdx.x * 256 + threadIdx.x;
    if (e < E) rank[e] = atomicAdd(&counts[dst[e]], 1);
}

// ---- 3-phase multi-block exclusive scan over counts (N ~ 50000) ----------
__global__ __launch_bounds__(256) void scan_phase1(const int* __restrict__ counts,
                                                   int* __restrict__ blockSums, int N) {
    int i = blockIdx.x * 256 + threadIdx.x;
    int v = (i < N) ? counts[i] : 0;
    #pragma unroll
    for (int o = 32; o >= 1; o >>= 1) v += __shfl_xor(v, o, 64);
    __shared__ int ws[4];
    int lane = threadIdx.x & 63, w = threadIdx.x >> 6;
    if (lane == 0) ws[w] = v;
    __syncthreads();
    if (threadIdx.x == 0) blockSums[blockIdx.x] = ws[0] + ws[1] + ws[2] + ws[3];
}

// exclusive scan of blockSums in place (nb <= 256)
__global__ __launch_bounds__(256) void scan_phase2(int* __restrict__ blockSums, int nb) {
    __shared__ int s[256];
    int tid = threadIdx.x;
    int v = (tid < nb) ? blockSums[tid] : 0;
    s[tid] = v;
    __syncthreads();
    for (int off = 1; off < 256; off <<= 1) {
        int t = (tid >= off) ? s[tid - off] : 0;
        __syncthreads();
        s[tid] += t;
        __syncthreads();
    }
    if (tid < nb) blockSums[tid] = s[tid] - v;
}

// per-block exclusive scan + block offset -> offs[]; fused rsq = rsqrt(deg+1)
__global__ __launch_bounds__(256) void scan_phase3(const int* __restrict__ counts,
                                                   const int* __restrict__ blockSums,
                                                   int* __restrict__ offs,
                                                   float* __restrict__ rsq, int N) {
    __shared__ int s[256];
    int tid = threadIdx.x;
    int i = blockIdx.x * 256 + tid;
    int c = (i < N) ? counts[i] : 0;
    s[tid] = c;
    __syncthreads();
    for (int off = 1; off < 256; off <<= 1) {
        int t = (tid >= off) ? s[tid - off] : 0;
        __syncthreads();
        s[tid] += t;
        __syncthreads();
    }
    if (i < N) {
        int excl = s[tid] - c + blockSums[blockIdx.x];
        offs[i] = excl;
        rsq[i] = rsqrtf((float)c + 1.0f);
        if (i == N - 1) offs[N] = excl + c;
    }
}

// packed edge record: src index (16b, N<65536) | fp16 weight (16b). No atomics.
__global__ __launch_bounds__(256) void scatter_kernel(const int* __restrict__ src,
                                                      const int* __restrict__ dst,
                                                      const int* __restrict__ rank,
                                                      const int* __restrict__ offs,
                                                      const float* __restrict__ rsq,
                                                      unsigned* __restrict__ epk, int E) {
    int e = blockIdx.x * 256 + threadIdx.x;
    if (e < E) {
        int d = dst[e];
        int s = src[e];
        int pos = offs[d] + rank[e];
        float w = rsq[s] * rsq[d];
        epk[pos] = (unsigned)s |
                   ((unsigned)__half_as_ushort(__float2half_rn(w)) << 16);
    }
}

// ------------------------- dtype conversions -------------------------------

__global__ __launch_bounds__(256) void cvt_f2h_kernel(const float* __restrict__ in,
                                                      unsigned short* __restrict__ out,
                                                      int n4) {
    int i = blockIdx.x * 256 + threadIdx.x;
    if (i < n4) {
        float4 v = reinterpret_cast<const float4*>(in)[i];
        ushort4 o;
        o.x = __half_as_ushort(__float2half_rn(v.x));
        o.y = __half_as_ushort(__float2half_rn(v.y));
        o.z = __half_as_ushort(__float2half_rn(v.z));
        o.w = __half_as_ushort(__float2half_rn(v.w));
        reinterpret_cast<ushort4*>(out)[i] = o;
    }
}

// all four weight transposes (fp32 [K][Nc] -> fp16 [Nc][K]) in one kernel
__global__ __launch_bounds__(256) void wtrans_all_kernel(
        const float* __restrict__ W1, const float* __restrict__ W2,
        const float* __restrict__ W3, const float* __restrict__ W4,
        unsigned short* __restrict__ Wt1, unsigned short* __restrict__ Wt2,
        unsigned short* __restrict__ Wt3, unsigned short* __restrict__ Wt4) {
    int i = blockIdx.x * 256 + threadIdx.x;
    if (i < 32768) {                         // W1: 128x256
        int k = i >> 8, n = i & 255;
        Wt1[n * 128 + k] = __half_as_ushort(__float2half_rn(W1[i]));
    } else if (i < 98304) {                  // W2: 256x256
        int j = i - 32768; int k = j >> 8, n = j & 255;
        Wt2[n * 256 + k] = __half_as_ushort(__float2half_rn(W2[j]));
    } else if (i < 163840) {                 // W3: 256x256
        int j = i - 98304; int k = j >> 8, n = j & 255;
        Wt3[n * 256 + k] = __half_as_ushort(__float2half_rn(W3[j]));
    } else if (i < 174080) {                 // W4: 256x40
        int j = i - 163840; int k = j / 40, n = j - k * 40;
        Wt4[n * 256 + k] = __half_as_ushort(__float2half_rn(W4[j]));
    }
}

// ------------------------- fp16 row-per-wave aggregation -------------------
// out[n] = sum_e w_e * G[src_e] + (1/deg_n) * G[n]  (+bias) (+relu)
// One wave per node. H2 = half2 elements per lane (1 -> F=128, 2 -> F=256).
template <int H2, bool BIAS, bool RELU>
__global__ __launch_bounds__(256) void agg_f16_kernel(
        const unsigned* __restrict__ G,      // fp16 rows, 64*H2 dwords per row
        const int* __restrict__ offs,
        const unsigned* __restrict__ epk,
        const float* __restrict__ rsq,
        const float* __restrict__ bias,
        unsigned* __restrict__ out, int N) {
    constexpr int ROWU = 64 * H2;
    int lane = threadIdx.x & 63;
    int node = blockIdx.x * 4 + (threadIdx.x >> 6);
    if (node >= N) return;
    const unsigned* base = G + lane * H2;

    __half2 acc[H2];
    #pragma unroll
    for (int i = 0; i < H2; i++) acc[i] = u2h2(0u);

    int e = offs[node], e1 = offs[node + 1];
    for (; e + 3 < e1; e += 4) {
        unsigned p[4];
        int s[4];
        #pragma unroll
        for (int j = 0; j < 4; j++) { p[j] = epk[e + j]; s[j] = p[j] & 0xFFFFu; }
        unsigned g[4][H2];
        #pragma unroll
        for (int j = 0; j < 4; j++)
            #pragma unroll
            for (int i = 0; i < H2; i++)
                g[j][i] = base[(size_t)s[j] * ROWU + i];
        #pragma unroll
        for (int j = 0; j < 4; j++) {
            __half2 w2 = __half2half2(__ushort_as_half((unsigned short)(p[j] >> 16)));
            #pragma unroll
            for (int i = 0; i < H2; i++)
                acc[i] = __hfma2(w2, u2h2(g[j][i]), acc[i]);
        }
    }
    for (; e < e1; e++) {
        unsigned p0 = epk[e];
        int s0 = p0 & 0xFFFFu;
        __half2 w2 = __half2half2(__ushort_as_half((unsigned short)(p0 >> 16)));
        #pragma unroll
        for (int i = 0; i < H2; i++)
            acc[i] = __hfma2(w2, u2h2(base[(size_t)s0 * ROWU + i]), acc[i]);
    }

    float sn = rsq[node];
    sn *= sn;
    #pragma unroll
    for (int i = 0; i < H2; i++) {
        unsigned sv = base[(size_t)node * ROWU + i];
        float2 f = __half22float2(acc[i]);
        f.x = fmaf(sn, hlo(sv), f.x);
        f.y = fmaf(sn, hhi(sv), f.y);
        if (BIAS) {
            float2 b = reinterpret_cast<const float2*>(bias)[lane * H2 + i];
            f.x += b.x; f.y += b.y;
        }
        if (RELU) { f.x = fmaxf(f.x, 0.f); f.y = fmaxf(f.y, 0.f); }
        out[(size_t)node * ROWU + lane * H2 + i] = h22u(__floats2half2_rn(f.x, f.y));
    }
}

// ------------------------- agg (40 feats) + log_softmax --------------------
__global__ __launch_bounds__(256) void agg40_softmax_kernel(
        const unsigned* __restrict__ G,      // fp16 rows, 20 dwords per row
        const int* __restrict__ offs,
        const unsigned* __restrict__ epk,
        const float* __restrict__ rsq,
        const float* __restrict__ bias,
        float* __restrict__ out, int N) {
    int lane = threadIdx.x & 63;
    int node = blockIdx.x * 4 + (threadIdx.x >> 6);
    if (node >= N) return;
    bool act = lane < 20;
    __half2 acch = u2h2(0u);
    int e = offs[node], e1 = offs[node + 1];
    for (; e + 1 < e1; e += 2) {
        unsigned p0 = epk[e], p1 = epk[e + 1];
        if (act) {
            int s0 = p0 & 0xFFFFu, s1 = p1 & 0xFFFFu;
            __half2 w0 = __half2half2(__ushort_as_half((unsigned short)(p0 >> 16)));
            __half2 w1 = __half2half2(__ushort_as_half((unsigned short)(p1 >> 16)));
            unsigned g0 = G[(size_t)s0 * 20 + lane];
            unsigned g1 = G[(size_t)s1 * 20 + lane];
            acch = __hfma2(w0, u2h2(g0), acch);
            acch = __hfma2(w1, u2h2(g1), acch);
        }
    }
    if (e < e1 && act) {
        unsigned p0 = epk[e];
        int s0 = p0 & 0xFFFFu;
        __half2 w0 = __half2half2(__ushort_as_half((unsigned short)(p0 >> 16)));
        acch = __hfma2(w0, u2h2(G[(size_t)s0 * 20 + lane]), acch);
    }
    float lo = 0.f, hi = 0.f;
    if (act) {
        float sn = rsq[node];
        sn *= sn;
        unsigned sv = G[(size_t)node * 20 + lane];
        float2 f = __half22float2(acch);
        lo = fmaf(sn, hlo(sv), f.x) + bias[2 * lane];
        hi = fmaf(sn, hhi(sv), f.y) + bias[2 * lane + 1];
    }
    float m = act ? fmaxf(lo, hi) : -INFINITY;
    #pragma unroll
    for (int o = 32; o >= 1; o >>= 1) m = fmaxf(m, __shfl_xor(m, o, 64));
    float s = act ? (expf(lo - m) + expf(hi - m)) : 0.f;
    #pragma unroll
    for (int o = 32; o >= 1; o >>= 1) s += __shfl_xor(s, o, 64);
    float ls = logf(s);
    if (act) {
        float2 o2;
        o2.x = lo - m - ls;
        o2.y = hi - m - ls;
        *reinterpret_cast<float2*>(out + (size_t)node * 40 + 2 * lane) = o2;
    }
}

// ------------------------- f16 MFMA GEMM -----------------------------------
// C[M][Nc] = A[M][K] @ Bt[Nc][K]^T  (+bias) (+relu), fp32 accum, fp16 out.
template <bool BIAS, bool RELU>
__global__ __launch_bounds__(256) void gemm_f16(
        const unsigned short* __restrict__ A,   // [M][K] fp16
        const unsigned short* __restrict__ Bt,  // [Nc][K] fp16
        const float* __restrict__ bias,
        unsigned short* __restrict__ Cout,
        int M, int K, int Nc) {
    __shared__ __align__(16) unsigned short As[128 * 72];
    __shared__ __align__(16) unsigned short Bs[128 * 72];
    int tid = threadIdx.x;
    int lane = tid & 63;
    int wid = tid >> 6;
    int rowBase = blockIdx.y * 128;
    int colBase = blockIdx.x * 128;
    int waveM = (wid & 1) * 64;
    int waveN = (wid >> 1) * 64;

    f32x4 acc[4][4] = {};
    int lrow = lane & 15;
    int kgrp = (lane >> 4) * 8;

    for (int k0 = 0; k0 < K; k0 += 64) {
        #pragma unroll
        for (int i = 0; i < 4; i++) {
            int c = tid + 256 * i;
            int row = c >> 3;
            int kp = (c & 7) * 8;
            int4 av = make_int4(0, 0, 0, 0);
            int gr = rowBase + row;
            if (gr < M)
                av = *reinterpret_cast<const int4*>(A + (size_t)gr * K + k0 + kp);
            *reinterpret_cast<int4*>(&As[row * 72 + kp]) = av;
            int4 bv = make_int4(0, 0, 0, 0);
            int gc = colBase + row;
            if (gc < Nc)
                bv = *reinterpret_cast<const int4*>(Bt + (size_t)gc * K + k0 + kp);
            *reinterpret_cast<int4*>(&Bs[row * 72 + kp]) = bv;
        }
        __syncthreads();
        #pragma unroll
        for (int kk = 0; kk < 64; kk += 32) {
            f16x8 af[4], bfr[4];
            #pragma unroll
            for (int t = 0; t < 4; t++) {
                af[t] = *reinterpret_cast<const f16x8*>(
                    &As[(waveM + t * 16 + lrow) * 72 + kk + kgrp]);
                bfr[t] = *reinterpret_cast<const f16x8*>(
                    &Bs[(waveN + t * 16 + lrow) * 72 + kk + kgrp]);
            }
            #pragma unroll
            for (int mt = 0; mt < 4; mt++)
                #pragma unroll
                for (int nt = 0; nt < 4; nt++)
                    acc[mt][nt] = __builtin_amdgcn_mfma_f32_16x16x32_f16(
                        af[mt], bfr[nt], acc[mt][nt], 0, 0, 0);
        }
        __syncthreads();
    }

    #pragma unroll
    for (int mt = 0; mt < 4; mt++) {
        #pragma unroll
        for (int r = 0; r < 4; r++) {
            int row = rowBase + waveM + mt * 16 + (lane >> 4) * 4 + r;
            if (row >= M) continue;
            #pragma unroll
            for (int nt = 0; nt < 4; nt++) {
                int col = colBase + waveN + nt * 16 + (lane & 15);
                if (col >= Nc) continue;
                float v = acc[mt][nt][r];
                if (BIAS) v += bias[col];
                if (RELU) v = fmaxf(v, 0.f);
                Cout[(size_t)row * Nc + col] = __half_as_ushort(__float2half_rn(v));
            }
        }
    }
}

// ---------------------------------------------------------------------------

extern "C" void kernel_launch(void* const* d_in, const int* in_sizes, int n_in,
                              void* d_out, int out_size, void* d_ws, size_t ws_size,
                              hipStream_t stream) {
    const float* x  = (const float*)d_in[0];
    const int*   ei = (const int*)d_in[1];
    const float* W1 = (const float*)d_in[2];
    const float* b1 = (const float*)d_in[3];
    const float* W2 = (const float*)d_in[4];
    const float* b2 = (const float*)d_in[5];
    const float* W3 = (const float*)d_in[6];
    const float* b3 = (const float*)d_in[7];
    const float* W4 = (const float*)d_in[8];
    const float* b4 = (const float*)d_in[9];

    const int FIN = 128, HID = 256, C = 40;
    const int N = in_sizes[0] / FIN;   // 50000 (< 65536, required by edge pack)
    const int E = in_sizes[1] / 2;
    const int* src = ei;
    const int* dst = ei + E;

    char* w = (char*)d_ws;
    auto alloc = [&](size_t bytes) {
        char* p = w;
        w += (bytes + 255) & ~(size_t)255;
        return p;
    };
    int nScanBlocks = (N + 255) / 256;
    int*   counts = (int*)alloc((size_t)N * 4);
    int*   offs   = (int*)alloc((size_t)(N + 1) * 4);
    float* rsq    = (float*)alloc((size_t)N * 4);
    int*   bsums  = (int*)alloc((size_t)nScanBlocks * 4);
    int*   rank   = (int*)alloc((size_t)E * 4);
    unsigned* epk = (unsigned*)alloc((size_t)E * 4);
    unsigned short* xb   = (unsigned short*)alloc((size_t)N * FIN * 2);
    unsigned short* aggx = (unsigned short*)alloc((size_t)N * FIN * 2);
    unsigned short* bufA = (unsigned short*)alloc((size_t)N * HID * 2);
    unsigned short* bufB = (unsigned short*)alloc((size_t)N * HID * 2);
    unsigned short* Wt1 = (unsigned short*)alloc((size_t)FIN * HID * 2);
    unsigned short* Wt2 = (unsigned short*)alloc((size_t)HID * HID * 2);
    unsigned short* Wt3 = (unsigned short*)alloc((size_t)HID * HID * 2);
    unsigned short* Wt4 = (unsigned short*)alloc((size_t)HID * C * 2);

    hipMemsetAsync(counts, 0, (size_t)N * 4, stream);

    cvt_f2h_kernel<<<(N * FIN / 4 + 255) / 256, 256, 0, stream>>>(x, xb, N * FIN / 4);
    wtrans_all_kernel<<<680, 256, 0, stream>>>(W1, W2, W3, W4, Wt1, Wt2, Wt3, Wt4);

    count_kernel<<<(E + 255) / 256, 256, 0, stream>>>(dst, counts, rank, E);
    scan_phase1<<<nScanBlocks, 256, 0, stream>>>(counts, bsums, N);
    scan_phase2<<<1, 256, 0, stream>>>(bsums, nScanBlocks);
    scan_phase3<<<nScanBlocks, 256, 0, stream>>>(counts, bsums, offs, rsq, N);
    scatter_kernel<<<(E + 255) / 256, 256, 0, stream>>>(src, dst, rank, offs, rsq,
                                                        epk, E);

    int grp = (N + 3) / 4;
    dim3 gHID((HID + 127) / 128, (N + 127) / 128);
    dim3 gC((C + 127) / 128, (N + 127) / 128);

    // Layer 1: aggregate x (128 feats) then GEMM(+b1, relu)
    agg_f16_kernel<1, false, false>
        <<<grp, 256, 0, stream>>>((const unsigned*)xb, offs, epk, rsq, nullptr,
                                  (unsigned*)aggx, N);
    gemm_f16<true, true><<<gHID, 256, 0, stream>>>(aggx, Wt1, b1, bufA, N, FIN, HID);
    // Layer 2: GEMM -> agg(+b2, relu)
    gemm_f16<false, false><<<gHID, 256, 0, stream>>>(bufA, Wt2, nullptr, bufB,
                                                     N, HID, HID);
    agg_f16_kernel<2, true, true>
        <<<grp, 256, 0, stream>>>((const unsigned*)bufB, offs, epk, rsq, b2,
                                  (unsigned*)bufA, N);
    // Layer 3: GEMM -> agg(+b3, relu)
    gemm_f16<false, false><<<gHID, 256, 0, stream>>>(bufA, Wt3, nullptr, bufB,
                                                     N, HID, HID);
    agg_f16_kernel<2, true, true>
        <<<grp, 256, 0, stream>>>((const unsigned*)bufB, offs, epk, rsq, b3,
                                  (unsigned*)bufA, N);
    // Layer 4: GEMM (Nc=40) -> agg(+b4) + log_softmax fused
    gemm_f16<false, false><<<gC, 256, 0, stream>>>(bufA, Wt4, nullptr, bufB,
                                                   N, HID, C);
    agg40_softmax_kernel<<<grp, 256, 0, stream>>>((const unsigned*)bufB, offs, epk,
                                                  rsq, b4, (float*)d_out, N);
}

// Round 6
// 631.906 us; speedup vs baseline: 1.8635x; 1.0534x over previous
//
#include <hip/hip_runtime.h>
#include <hip/hip_fp16.h>
#include <math.h>

// ---------------------------------------------------------------------------
// GCN 4-layer forward, round 6:
//  - round-5 structure; agg edge-loop unrolled 8 with hoisted gathers
//    (latency-bound -> double memory-level parallelism)
//  - cvt + weight transpose fused into one kernel
// ---------------------------------------------------------------------------

typedef _Float16 f16x8 __attribute__((ext_vector_type(8)));
typedef float f32x4 __attribute__((ext_vector_type(4)));

__device__ __forceinline__ __half2 u2h2(unsigned u) {
    union { unsigned u; __half2 h; } v; v.u = u; return v.h;
}
__device__ __forceinline__ unsigned h22u(__half2 h) {
    union { unsigned u; __half2 h; } v; v.h = h; return v.u;
}
__device__ __forceinline__ float hlo(unsigned u) {
    return __half2float(__ushort_as_half((unsigned short)(u & 0xFFFFu)));
}
__device__ __forceinline__ float hhi(unsigned u) {
    return __half2float(__ushort_as_half((unsigned short)(u >> 16)));
}

// ------------------------- CSR build ---------------------------------------

__global__ __launch_bounds__(256) void count_kernel(const int* __restrict__ dst,
                                                    int* __restrict__ counts,
                                                    int* __restrict__ rank, int E) {
    int e = blockIdx.x * 256 + threadIdx.x;
    if (e < E) rank[e] = atomicAdd(&counts[dst[e]], 1);
}

__global__ __launch_bounds__(256) void scan_phase1(const int* __restrict__ counts,
                                                   int* __restrict__ blockSums, int N) {
    int i = blockIdx.x * 256 + threadIdx.x;
    int v = (i < N) ? counts[i] : 0;
    #pragma unroll
    for (int o = 32; o >= 1; o >>= 1) v += __shfl_xor(v, o, 64);
    __shared__ int ws[4];
    int lane = threadIdx.x & 63, w = threadIdx.x >> 6;
    if (lane == 0) ws[w] = v;
    __syncthreads();
    if (threadIdx.x == 0) blockSums[blockIdx.x] = ws[0] + ws[1] + ws[2] + ws[3];
}

__global__ __launch_bounds__(256) void scan_phase2(int* __restrict__ blockSums, int nb) {
    __shared__ int s[256];
    int tid = threadIdx.x;
    int v = (tid < nb) ? blockSums[tid] : 0;
    s[tid] = v;
    __syncthreads();
    for (int off = 1; off < 256; off <<= 1) {
        int t = (tid >= off) ? s[tid - off] : 0;
        __syncthreads();
        s[tid] += t;
        __syncthreads();
    }
    if (tid < nb) blockSums[tid] = s[tid] - v;
}

__global__ __launch_bounds__(256) void scan_phase3(const int* __restrict__ counts,
                                                   const int* __restrict__ blockSums,
                                                   int* __restrict__ offs,
                                                   float* __restrict__ rsq, int N) {
    __shared__ int s[256];
    int tid = threadIdx.x;
    int i = blockIdx.x * 256 + tid;
    int c = (i < N) ? counts[i] : 0;
    s[tid] = c;
    __syncthreads();
    for (int off = 1; off < 256; off <<= 1) {
        int t = (tid >= off) ? s[tid - off] : 0;
        __syncthreads();
        s[tid] += t;
        __syncthreads();
    }
    if (i < N) {
        int excl = s[tid] - c + blockSums[blockIdx.x];
        offs[i] = excl;
        rsq[i] = rsqrtf((float)c + 1.0f);
        if (i == N - 1) offs[N] = excl + c;
    }
}

__global__ __launch_bounds__(256) void scatter_kernel(const int* __restrict__ src,
                                                      const int* __restrict__ dst,
                                                      const int* __restrict__ rank,
                                                      const int* __restrict__ offs,
                                                      const float* __restrict__ rsq,
                                                      unsigned* __restrict__ epk, int E) {
    int e = blockIdx.x * 256 + threadIdx.x;
    if (e < E) {
        int d = dst[e];
        int s = src[e];
        int pos = offs[d] + rank[e];
        float w = rsq[s] * rsq[d];
        epk[pos] = (unsigned)s |
                   ((unsigned)__half_as_ushort(__float2half_rn(w)) << 16);
    }
}

// ------------------- fused cvt(x) + weight transposes ----------------------
// job 0: x (N*128 floats) -> fp16, 4 per thread
// jobs 1..4: W [K][Nc] fp32 -> Wt [Nc][K] fp16
__global__ __launch_bounds__(256) void prep_kernel(
        const float* __restrict__ x, unsigned short* __restrict__ xb, int nx4,
        const float* __restrict__ W1, const float* __restrict__ W2,
        const float* __restrict__ W3, const float* __restrict__ W4,
        unsigned short* __restrict__ Wt1, unsigned short* __restrict__ Wt2,
        unsigned short* __restrict__ Wt3, unsigned short* __restrict__ Wt4) {
    int i = blockIdx.x * 256 + threadIdx.x;
    if (i < nx4) {
        float4 v = reinterpret_cast<const float4*>(x)[i];
        ushort4 o;
        o.x = __half_as_ushort(__float2half_rn(v.x));
        o.y = __half_as_ushort(__float2half_rn(v.y));
        o.z = __half_as_ushort(__float2half_rn(v.z));
        o.w = __half_as_ushort(__float2half_rn(v.w));
        reinterpret_cast<ushort4*>(xb)[i] = o;
        return;
    }
    int j = i - nx4;
    if (j < 32768) {                         // W1: 128x256
        int k = j >> 8, n = j & 255;
        Wt1[n * 128 + k] = __half_as_ushort(__float2half_rn(W1[j]));
    } else if (j < 98304) {                  // W2: 256x256
        int t = j - 32768; int k = t >> 8, n = t & 255;
        Wt2[n * 256 + k] = __half_as_ushort(__float2half_rn(W2[t]));
    } else if (j < 163840) {                 // W3: 256x256
        int t = j - 98304; int k = t >> 8, n = t & 255;
        Wt3[n * 256 + k] = __half_as_ushort(__float2half_rn(W3[t]));
    } else if (j < 174080) {                 // W4: 256x40
        int t = j - 163840; int k = t / 40, n = t - k * 40;
        Wt4[n * 256 + k] = __half_as_ushort(__float2half_rn(W4[t]));
    }
}

// ------------------------- fp16 row-per-wave aggregation -------------------
// out[n] = sum_e w_e * G[src_e] + (1/deg_n) * G[n]  (+bias) (+relu)
// One wave per node. H2 = half2 elements per lane. 8-edge unroll, all
// gathers hoisted -> 8*H2 outstanding loads per lane for latency hiding.
template <int H2, bool BIAS, bool RELU>
__global__ __launch_bounds__(256) void agg_f16_kernel(
        const unsigned* __restrict__ G,      // fp16 rows, 64*H2 dwords per row
        const int* __restrict__ offs,
        const unsigned* __restrict__ epk,
        const float* __restrict__ rsq,
        const float* __restrict__ bias,
        unsigned* __restrict__ out, int N) {
    constexpr int ROWU = 64 * H2;
    constexpr int UNR = 8;
    int lane = threadIdx.x & 63;
    int node = blockIdx.x * 4 + (threadIdx.x >> 6);
    if (node >= N) return;
    const unsigned* base = G + lane * H2;

    __half2 acc[H2];
    #pragma unroll
    for (int i = 0; i < H2; i++) acc[i] = u2h2(0u);

    int e = offs[node], e1 = offs[node + 1];
    for (; e + UNR - 1 < e1; e += UNR) {
        unsigned p[UNR];
        int s[UNR];
        #pragma unroll
        for (int j = 0; j < UNR; j++) { p[j] = epk[e + j]; s[j] = p[j] & 0xFFFFu; }
        unsigned g[UNR][H2];
        #pragma unroll
        for (int j = 0; j < UNR; j++)
            #pragma unroll
            for (int i = 0; i < H2; i++)
                g[j][i] = base[(size_t)s[j] * ROWU + i];
        #pragma unroll
        for (int j = 0; j < UNR; j++) {
            __half2 w2 = __half2half2(__ushort_as_half((unsigned short)(p[j] >> 16)));
            #pragma unroll
            for (int i = 0; i < H2; i++)
                acc[i] = __hfma2(w2, u2h2(g[j][i]), acc[i]);
        }
    }
    for (; e < e1; e++) {
        unsigned p0 = epk[e];
        int s0 = p0 & 0xFFFFu;
        __half2 w2 = __half2half2(__ushort_as_half((unsigned short)(p0 >> 16)));
        #pragma unroll
        for (int i = 0; i < H2; i++)
            acc[i] = __hfma2(w2, u2h2(base[(size_t)s0 * ROWU + i]), acc[i]);
    }

    float sn = rsq[node];
    sn *= sn;
    #pragma unroll
    for (int i = 0; i < H2; i++) {
        unsigned sv = base[(size_t)node * ROWU + i];
        float2 f = __half22float2(acc[i]);
        f.x = fmaf(sn, hlo(sv), f.x);
        f.y = fmaf(sn, hhi(sv), f.y);
        if (BIAS) {
            float2 b = reinterpret_cast<const float2*>(bias)[lane * H2 + i];
            f.x += b.x; f.y += b.y;
        }
        if (RELU) { f.x = fmaxf(f.x, 0.f); f.y = fmaxf(f.y, 0.f); }
        out[(size_t)node * ROWU + lane * H2 + i] = h22u(__floats2half2_rn(f.x, f.y));
    }
}

// ------------------------- agg (40 feats) + log_softmax --------------------
__global__ __launch_bounds__(256) void agg40_softmax_kernel(
        const unsigned* __restrict__ G,      // fp16 rows, 20 dwords per row
        const int* __restrict__ offs,
        const unsigned* __restrict__ epk,
        const float* __restrict__ rsq,
        const float* __restrict__ bias,
        float* __restrict__ out, int N) {
    int lane = threadIdx.x & 63;
    int node = blockIdx.x * 4 + (threadIdx.x >> 6);
    if (node >= N) return;
    bool act = lane < 20;
    int cl = act ? lane : 0;
    __half2 acch = u2h2(0u);
    int e = offs[node], e1 = offs[node + 1];
    for (; e + 3 < e1; e += 4) {
        unsigned p[4];
        int s[4];
        #pragma unroll
        for (int j = 0; j < 4; j++) { p[j] = epk[e + j]; s[j] = p[j] & 0xFFFFu; }
        unsigned g[4];
        #pragma unroll
        for (int j = 0; j < 4; j++) g[j] = G[(size_t)s[j] * 20 + cl];
        #pragma unroll
        for (int j = 0; j < 4; j++) {
            __half2 w = __half2half2(__ushort_as_half((unsigned short)(p[j] >> 16)));
            acch = __hfma2(w, u2h2(g[j]), acch);
        }
    }
    for (; e < e1; e++) {
        unsigned p0 = epk[e];
        int s0 = p0 & 0xFFFFu;
        __half2 w0 = __half2half2(__ushort_as_half((unsigned short)(p0 >> 16)));
        acch = __hfma2(w0, u2h2(G[(size_t)s0 * 20 + cl]), acch);
    }
    float lo = 0.f, hi = 0.f;
    if (act) {
        float sn = rsq[node];
        sn *= sn;
        unsigned sv = G[(size_t)node * 20 + lane];
        float2 f = __half22float2(acch);
        lo = fmaf(sn, hlo(sv), f.x) + bias[2 * lane];
        hi = fmaf(sn, hhi(sv), f.y) + bias[2 * lane + 1];
    }
    float m = act ? fmaxf(lo, hi) : -INFINITY;
    #pragma unroll
    for (int o = 32; o >= 1; o >>= 1) m = fmaxf(m, __shfl_xor(m, o, 64));
    float s = act ? (expf(lo - m) + expf(hi - m)) : 0.f;
    #pragma unroll
    for (int o = 32; o >= 1; o >>= 1) s += __shfl_xor(s, o, 64);
    float ls = logf(s);
    if (act) {
        float2 o2;
        o2.x = lo - m - ls;
        o2.y = hi - m - ls;
        *reinterpret_cast<float2*>(out + (size_t)node * 40 + 2 * lane) = o2;
    }
}

// ------------------------- f16 MFMA GEMM -----------------------------------
// C[M][Nc] = A[M][K] @ Bt[Nc][K]^T  (+bias) (+relu), fp32 accum, fp16 out.
template <bool BIAS, bool RELU>
__global__ __launch_bounds__(256) void gemm_f16(
        const unsigned short* __restrict__ A,   // [M][K] fp16
        const unsigned short* __restrict__ Bt,  // [Nc][K] fp16
        const float* __restrict__ bias,
        unsigned short* __restrict__ Cout,
        int M, int K, int Nc) {
    __shared__ __align__(16) unsigned short As[128 * 72];
    __shared__ __align__(16) unsigned short Bs[128 * 72];
    int tid = threadIdx.x;
    int lane = tid & 63;
    int wid = tid >> 6;
    int rowBase = blockIdx.y * 128;
    int colBase = blockIdx.x * 128;
    int waveM = (wid & 1) * 64;
    int waveN = (wid >> 1) * 64;

    f32x4 acc[4][4] = {};
    int lrow = lane & 15;
    int kgrp = (lane >> 4) * 8;

    for (int k0 = 0; k0 < K; k0 += 64) {
        #pragma unroll
        for (int i = 0; i < 4; i++) {
            int c = tid + 256 * i;
            int row = c >> 3;
            int kp = (c & 7) * 8;
            int4 av = make_int4(0, 0, 0, 0);
            int gr = rowBase + row;
            if (gr < M)
                av = *reinterpret_cast<const int4*>(A + (size_t)gr * K + k0 + kp);
            *reinterpret_cast<int4*>(&As[row * 72 + kp]) = av;
            int4 bv = make_int4(0, 0, 0, 0);
            int gc = colBase + row;
            if (gc < Nc)
                bv = *reinterpret_cast<const int4*>(Bt + (size_t)gc * K + k0 + kp);
            *reinterpret_cast<int4*>(&Bs[row * 72 + kp]) = bv;
        }
        __syncthreads();
        #pragma unroll
        for (int kk = 0; kk < 64; kk += 32) {
            f16x8 af[4], bfr[4];
            #pragma unroll
            for (int t = 0; t < 4; t++) {
                af[t] = *reinterpret_cast<const f16x8*>(
                    &As[(waveM + t * 16 + lrow) * 72 + kk + kgrp]);
                bfr[t] = *reinterpret_cast<const f16x8*>(
                    &Bs[(waveN + t * 16 + lrow) * 72 + kk + kgrp]);
            }
            #pragma unroll
            for (int mt = 0; mt < 4; mt++)
                #pragma unroll
                for (int nt = 0; nt < 4; nt++)
                    acc[mt][nt] = __builtin_amdgcn_mfma_f32_16x16x32_f16(
                        af[mt], bfr[nt], acc[mt][nt], 0, 0, 0);
        }
        __syncthreads();
    }

    #pragma unroll
    for (int mt = 0; mt < 4; mt++) {
        #pragma unroll
        for (int r = 0; r < 4; r++) {
            int row = rowBase + waveM + mt * 16 + (lane >> 4) * 4 + r;
            if (row >= M) continue;
            #pragma unroll
            for (int nt = 0; nt < 4; nt++) {
                int col = colBase + waveN + nt * 16 + (lane & 15);
                if (col >= Nc) continue;
                float v = acc[mt][nt][r];
                if (BIAS) v += bias[col];
                if (RELU) v = fmaxf(v, 0.f);
                Cout[(size_t)row * Nc + col] = __half_as_ushort(__float2half_rn(v));
            }
        }
    }
}

// ---------------------------------------------------------------------------

extern "C" void kernel_launch(void* const* d_in, const int* in_sizes, int n_in,
                              void* d_out, int out_size, void* d_ws, size_t ws_size,
                              hipStream_t stream) {
    const float* x  = (const float*)d_in[0];
    const int*   ei = (const int*)d_in[1];
    const float* W1 = (const float*)d_in[2];
    const float* b1 = (const float*)d_in[3];
    const float* W2 = (const float*)d_in[4];
    const float* b2 = (const float*)d_in[5];
    const float* W3 = (const float*)d_in[6];
    const float* b3 = (const float*)d_in[7];
    const float* W4 = (const float*)d_in[8];
    const float* b4 = (const float*)d_in[9];

    const int FIN = 128, HID = 256, C = 40;
    const int N = in_sizes[0] / FIN;   // 50000 (< 65536, required by edge pack)
    const int E = in_sizes[1] / 2;
    const int* src = ei;
    const int* dst = ei + E;

    char* w = (char*)d_ws;
    auto alloc = [&](size_t bytes) {
        char* p = w;
        w += (bytes + 255) & ~(size_t)255;
        return p;
    };
    int nScanBlocks = (N + 255) / 256;
    int*   counts = (int*)alloc((size_t)N * 4);
    int*   offs   = (int*)alloc((size_t)(N + 1) * 4);
    float* rsq    = (float*)alloc((size_t)N * 4);
    int*   bsums  = (int*)alloc((size_t)nScanBlocks * 4);
    int*   rank   = (int*)alloc((size_t)E * 4);
    unsigned* epk = (unsigned*)alloc((size_t)E * 4);
    unsigned short* xb   = (unsigned short*)alloc((size_t)N * FIN * 2);
    unsigned short* aggx = (unsigned short*)alloc((size_t)N * FIN * 2);
    unsigned short* bufA = (unsigned short*)alloc((size_t)N * HID * 2);
    unsigned short* bufB = (unsigned short*)alloc((size_t)N * HID * 2);
    unsigned short* Wt1 = (unsigned short*)alloc((size_t)FIN * HID * 2);
    unsigned short* Wt2 = (unsigned short*)alloc((size_t)HID * HID * 2);
    unsigned short* Wt3 = (unsigned short*)alloc((size_t)HID * HID * 2);
    unsigned short* Wt4 = (unsigned short*)alloc((size_t)HID * C * 2);

    hipMemsetAsync(counts, 0, (size_t)N * 4, stream);

    int nx4 = N * FIN / 4;
    prep_kernel<<<(nx4 + 174080 + 255) / 256, 256, 0, stream>>>(
        x, xb, nx4, W1, W2, W3, W4, Wt1, Wt2, Wt3, Wt4);

    count_kernel<<<(E + 255) / 256, 256, 0, stream>>>(dst, counts, rank, E);
    scan_phase1<<<nScanBlocks, 256, 0, stream>>>(counts, bsums, N);
    scan_phase2<<<1, 256, 0, stream>>>(bsums, nScanBlocks);
    scan_phase3<<<nScanBlocks, 256, 0, stream>>>(counts, bsums, offs, rsq, N);
    scatter_kernel<<<(E + 255) / 256, 256, 0, stream>>>(src, dst, rank, offs, rsq,
                                                        epk, E);

    int grp = (N + 3) / 4;
    dim3 gHID((HID + 127) / 128, (N + 127) / 128);
    dim3 gC((C + 127) / 128, (N + 127) / 128);

    // Layer 1: aggregate x (128 feats) then GEMM(+b1, relu)
    agg_f16_kernel<1, false, false>
        <<<grp, 256, 0, stream>>>((const unsigned*)xb, offs, epk, rsq, nullptr,
                                  (unsigned*)aggx, N);
    gemm_f16<true, true><<<gHID, 256, 0, stream>>>(aggx, Wt1, b1, bufA, N, FIN, HID);
    // Layer 2: GEMM -> agg(+b2, relu)
    gemm_f16<false, false><<<gHID, 256, 0, stream>>>(bufA, Wt2, nullptr, bufB,
                                                     N, HID, HID);
    agg_f16_kernel<2, true, true>
        <<<grp, 256, 0, stream>>>((const unsigned*)bufB, offs, epk, rsq, b2,
                                  (unsigned*)bufA, N);
    // Layer 3: GEMM -> agg(+b3, relu)
    gemm_f16<false, false><<<gHID, 256, 0, stream>>>(bufA, Wt3, nullptr, bufB,
                                                     N, HID, HID);
    agg_f16_kernel<2, true, true>
        <<<grp, 256, 0, stream>>>((const unsigned*)bufB, offs, epk, rsq, b3,
                                  (unsigned*)bufA, N);
    // Layer 4: GEMM (Nc=40) -> agg(+b4) + log_softmax fused
    gemm_f16<false, false><<<gC, 256, 0, stream>>>(bufA, Wt4, nullptr, bufB,
                                                   N, HID, C);
    agg40_softmax_kernel<<<grp, 256, 0, stream>>>((const unsigned*)bufB, offs, epk,
                                                  rsq, b4, (float*)d_out, N);
}